// Round 14
// baseline (188.556 us; speedup 1.0000x reference)
//
#include <hip/hip_runtime.h>
#include <hip/hip_bf16.h>

#define B_   32
#define L_   2048
#define CIN  256
#define HID  512
#define TL   16
#define NLT  (L_ / TL)        // 128 tiles of 16 rows per batch
#define NTILES (B_ * NLT)     // 4096 blocks

typedef __bf16 bf16_t;
typedef __bf16 bf16x8 __attribute__((ext_vector_type(8)));
typedef __bf16 bf16x4 __attribute__((ext_vector_type(4)));
typedef float  f32x4  __attribute__((ext_vector_type(4)));

// LDS map (16 KB): A(x)@0 8K, A(y)@8K. Nothing else.
#define AX_OFF 0u
#define AY_OFF 8192u

// ---------------------------------------------------------------------------
// Kernel 1: compose Wc = W2 @ W1 (fp32 math -> bf16), bc = W2 @ b1 + b2.
// No activation between the two 1x1 convs -> one projection, 3x fewer FLOPs.
// 64 blocks x 8 g-rows each: W1 is streamed once per block (32 MB total L2
// traffic instead of 256 MB with one-row blocks).
// ---------------------------------------------------------------------------
__global__ void compose_kernel(const float* __restrict__ W1, const float* __restrict__ W2,
                               const float* __restrict__ b1, const float* __restrict__ b2,
                               bf16_t* __restrict__ Wc, float* __restrict__ bc)
{
    const int g0 = blockIdx.x * 8;       // 64 blocks
    const int c  = threadIdx.x;          // 256
    float acc[8] = {0.f, 0.f, 0.f, 0.f, 0.f, 0.f, 0.f, 0.f};
    for (int h = 0; h < HID; ++h) {
        const float w1 = W1[(size_t)h * CIN + c];   // coalesced row
#pragma unroll
        for (int k = 0; k < 8; ++k)                 // W2[g0+k][h]: uniform -> s_load
            acc[k] = fmaf(W2[(size_t)(g0 + k) * HID + h], w1, acc[k]);
    }
#pragma unroll
    for (int k = 0; k < 8; ++k)
        Wc[(size_t)(g0 + k) * CIN + c] = (bf16_t)acc[k];
    if (c < 8) {                          // bc[g0+c] = W2[g0+c,:] . b1 + b2
        const float* w2row = W2 + (size_t)(g0 + c) * HID;
        float t0 = 0.f, t1 = 0.f;
        for (int h = 0; h < HID; h += 2) {
            t0 = fmaf(w2row[h], b1[h], t0);
            t1 = fmaf(w2row[h + 1], b1[h + 1], t1);
        }
        bc[g0 + c] = t0 + t1 + b2[g0 + c];
    }
}

// ---------------------------------------------------------------------------
// Kernel 2: fused single-GEMM + tanh-pair-product + row-reduction.
// R10's proven-no-spill shape (44 arch VGPR measured) + composed Wc:
// 4096 blocks x 512 thr (8 waves) on one 16-row tile, full 512 cols.
// Wave w owns cols [w*64, w*64+64) (cj=0..3), rows 0..15 (= l15), BOTH
// pipes. acc = 32 AGPR; arch stays ~45 (psum 16 + w 16 + frags 8 + addr).
// The 14-round register rule: at (...,4) the compiler pins arch <= 64 —
// this is the only structure measured UNDER it with margin.
// LDS 16 KB, no prefetch, 1 barrier; ~76 total regs -> 6 waves/SIMD ->
// 3 blocks/CU co-resident: cross-block TLP hides stage + Wc-L2 latency
// (R10's real problem was 768 KB weights/block; Wc is 256 KB and the
// FLOPs are 3x fewer).
// ---------------------------------------------------------------------------
__global__ __launch_bounds__(512, 4)
void fused_kernel(const float* __restrict__ x, const float* __restrict__ y,
                  const bf16_t* __restrict__ Wc, const float* __restrict__ bc,
                  float* __restrict__ partial)
{
    __shared__ char U[16384];            // 16 KB

    const int tid  = threadIdx.x;
    const int lane = tid & 63;
    const int wv   = tid >> 6;           // wave 0..7
    const int l15  = lane & 15;
    const int l4   = lane >> 4;
    const int col0 = wv * 64;            // this wave's output-col base
    const int tile = blockIdx.x;

    // --- stage [16 x CIN] fp32 -> bf16, swizzled. thr 0-255 x, 256-511 y;
    // 16 thr/row, 4 float4 each (coalesced 16-thread bursts).
    {
        const int sp = tid >> 8;
        const int t8 = tid & 255;
        const int sr = t8 >> 4;          // row 0..15
        const int sq = t8 & 15;          // float4 slot
        const float4* s4 = reinterpret_cast<const float4*>(
            (sp ? y : x) + ((size_t)tile * TL + sr) * CIN);
        char* rowp = U + (sp ? AY_OFF : AX_OFF) + sr * 512;
        const unsigned swz = (unsigned)((sr & 15) << 4);
#pragma unroll
        for (int c = 0; c < 4; ++c) {
            float4 vv = s4[sq + 16 * c];
            bf16x4 h;
            h[0] = (bf16_t)vv.x; h[1] = (bf16_t)vv.y;
            h[2] = (bf16_t)vv.z; h[3] = (bf16_t)vv.w;
            *reinterpret_cast<bf16x4*>(rowp + (((unsigned)(8 * (sq + 16 * c))) ^ swz)) = h;
        }
    }
    __syncthreads();                     // A(x), A(y) ready

    const unsigned fswz = (unsigned)((l15 & 15) << 4);   // fragment-row swizzle
    const unsigned fcol = ((unsigned)(l4 * 16)) ^ fswz;  // per-kk addr = base ^ (kk<<6)

    // ---- GEMM both pipes (shared Wc stream), bias bc folded into acc init
    f32x4 accx[4], accy[4];              // [cj] : 32 AGPR total
#pragma unroll
    for (int cj = 0; cj < 4; ++cj) {
        float4 bv = *reinterpret_cast<const float4*>(bc + col0 + cj * 16 + l4 * 4);
        f32x4 bi = (f32x4){bv.x, bv.y, bv.z, bv.w};
        accx[cj] = bi; accy[cj] = bi;
    }
    for (int kk = 0; kk < CIN / 32; ++kk) {
        bf16x8 w[4];
#pragma unroll
        for (int cj = 0; cj < 4; ++cj)
            w[cj] = *reinterpret_cast<const bf16x8*>(
                Wc + (size_t)(col0 + cj * 16 + l15) * CIN + kk * 32 + l4 * 8);
        const unsigned o = (unsigned)(l15 * 512) + (fcol ^ (unsigned)(kk << 6));
        bf16x8 ax = *reinterpret_cast<const bf16x8*>(U + AX_OFF + o);
        bf16x8 ay = *reinterpret_cast<const bf16x8*>(U + AY_OFF + o);
        __builtin_amdgcn_s_setprio(1);
#pragma unroll
        for (int cj = 0; cj < 4; ++cj) {
            accx[cj] = __builtin_amdgcn_mfma_f32_16x16x32_bf16(w[cj], ax, accx[cj], 0, 0, 0);
            accy[cj] = __builtin_amdgcn_mfma_f32_16x16x32_bf16(w[cj], ay, accy[cj], 0, 0, 0);
        }
        __builtin_amdgcn_s_setprio(0);
    }

    // ---- paired tanh product + reduce over the 16 rows (= l15 lanes).
    // tanh(a)tanh(b) = (Ea-1)(Eb-1)/((Ea+1)(Eb+1)), E = e^{2v} clamped.
    f32x4 psum[4];
#pragma unroll
    for (int cj = 0; cj < 4; ++cj) {
#pragma unroll
        for (int r2 = 0; r2 < 4; ++r2) {
            float a = fminf(fmaxf(accx[cj][r2], -9.0f), 9.0f);
            float c = fminf(fmaxf(accy[cj][r2], -9.0f), 9.0f);
            float Ea = exp2f(a * 2.885390081777927f);
            float Eb = exp2f(c * 2.885390081777927f);
            float num = (Ea - 1.0f) * (Eb - 1.0f);
            float den = (Ea + 1.0f) * (Eb + 1.0f);
            psum[cj][r2] = num * __builtin_amdgcn_rcpf(den);
        }
    }
#pragma unroll
    for (int cj = 0; cj < 4; ++cj)
#pragma unroll
        for (int r2 = 0; r2 < 4; ++r2) {
            float s = psum[cj][r2];
            s += __shfl_xor(s, 1);
            s += __shfl_xor(s, 2);
            s += __shfl_xor(s, 4);
            s += __shfl_xor(s, 8);
            psum[cj][r2] = s;
        }
    if (l15 == 0) {
#pragma unroll
        for (int cj = 0; cj < 4; ++cj) {
            float4 o4 = make_float4(psum[cj][0], psum[cj][1], psum[cj][2], psum[cj][3]);
            *reinterpret_cast<float4*>(partial + (size_t)tile * HID + col0 + cj * 16 + l4 * 4) = o4;
        }
    }
}

// ---------------------------------------------------------------------------
// Kernel 3: sum the 128 tile-partials per batch -> out[B][HID]
// ---------------------------------------------------------------------------
__global__ void reduce_kernel(const float* __restrict__ partial, float* __restrict__ out)
{
    int b = blockIdx.x;                  // 32
    int g = threadIdx.x;                 // 512
    float s = 0.f;
    for (int t = 0; t < NLT; ++t)
        s += partial[((size_t)(b * NLT + t)) * HID + g];
    out[b * HID + g] = s;
}

extern "C" void kernel_launch(void* const* d_in, const int* in_sizes, int n_in,
                              void* d_out, int out_size, void* d_ws, size_t ws_size,
                              hipStream_t stream)
{
    const float* x  = (const float*)d_in[0];
    const float* y  = (const float*)d_in[1];
    const float* W1 = (const float*)d_in[2];
    const float* b1 = (const float*)d_in[3];
    const float* W2 = (const float*)d_in[4];
    const float* b2 = (const float*)d_in[5];
    float* out = (float*)d_out;

    char* ws = (char*)d_ws;
    bf16_t* Wc     = (bf16_t*)ws;                    // 256 KB
    float*  bc     = (float*)(ws + (256 << 10));     // 2 KB
    float*  partial = (float*)(ws + (264 << 10));    // 8 MB (4096 tiles x 512)

    hipLaunchKernelGGL(compose_kernel, dim3(HID / 8), dim3(CIN), 0, stream, W1, W2, b1, b2, Wc, bc);
    hipLaunchKernelGGL(fused_kernel, dim3(NTILES), dim3(512), 0, stream, x, y, Wc, bc, partial);
    hipLaunchKernelGGL(reduce_kernel, dim3(B_), dim3(512), 0, stream, partial, out);
}

// Round 15
// 123.647 us; speedup vs baseline: 1.5249x; 1.5249x over previous
//
#include <hip/hip_runtime.h>
#include <hip/hip_bf16.h>

#define B_   32
#define L_   2048
#define CIN  256
#define HID  512
#define TL   16
#define TPT  32                    // tiles per block = 512 rows
#define NGRP (B_ * L_ / (TL * TPT))// 128 row-groups of 512 rows
#define NBLK (NGRP * 2)            // x2 G-halves = 256 blocks = 1 per CU

typedef __bf16 bf16_t;
typedef __bf16 bf16x8 __attribute__((ext_vector_type(8)));
typedef __bf16 bf16x4 __attribute__((ext_vector_type(4)));
typedef float  f32x4  __attribute__((ext_vector_type(4)));

// LDS map (144 KB): Wc-half @0 (256 cols x 512 B = 128 KB, swizzled);
// A tile @131072 (x @ +0, y @ +8192; 16 rows x 512 B each, swizzled).
#define WC_LDS 0u
#define A_LDS  131072u
#define LDS_BYTES 147456

// ---------------------------------------------------------------------------
// Kernel 1: compose Wc = W2 @ W1 (fp32 math -> bf16), bc = W2 @ b1 + b2.
// No activation between the two 1x1 convs -> one projection, 3x fewer FLOPs.
// ---------------------------------------------------------------------------
__global__ void compose_kernel(const float* __restrict__ W1, const float* __restrict__ W2,
                               const float* __restrict__ b1, const float* __restrict__ b2,
                               bf16_t* __restrict__ Wc, float* __restrict__ bc)
{
    const int g0 = blockIdx.x * 8;       // 64 blocks
    const int c  = threadIdx.x;          // 256
    float acc[8] = {0.f, 0.f, 0.f, 0.f, 0.f, 0.f, 0.f, 0.f};
    for (int h = 0; h < HID; ++h) {
        const float w1 = W1[(size_t)h * CIN + c];   // coalesced row
#pragma unroll
        for (int k = 0; k < 8; ++k)                 // W2[g0+k][h]: uniform
            acc[k] = fmaf(W2[(size_t)(g0 + k) * HID + h], w1, acc[k]);
    }
#pragma unroll
    for (int k = 0; k < 8; ++k)
        Wc[(size_t)(g0 + k) * CIN + c] = (bf16_t)acc[k];
    if (c < 8) {
        const float* w2row = W2 + (size_t)(g0 + c) * HID;
        float t0 = 0.f, t1 = 0.f;
        for (int h = 0; h < HID; h += 2) {
            t0 = fmaf(w2row[h], b1[h], t0);
            t1 = fmaf(w2row[h + 1], b1[h + 1], t1);
        }
        bc[g0 + c] = t0 + t1 + b2[g0 + c];
    }
}

// ---------------------------------------------------------------------------
// Kernel 2: fused GEMM + tanh-pair-product + row-reduction, with the weight
// stream moved to LDS (the R4..R14 invariant: every structure re-streamed
// 256 KB of weights per tile through L1/L2 -> 4 MB/CU, needing ~60 TB/s of
// L2 at the MFMA roofline. Here each CU reads its 128 KB Wc-half ONCE).
// 256 blocks (1/CU) x 512 thr (8 waves). Block (grp, half): 512 consecutive
// rows x 256 output cols. Wave w owns local cols [w*32,w*32+32) (cj=0,1),
// rows 0..15 (=l15), both pipes -> acc = 16 AGPR.
// Per tile: [issue v(t+1)] gemm(LDS w x LDS a) -> bar -> [write v(t+1)]
// tanh->psum -> bar. psum accumulates over 32 tiles; one store per block.
// Wc LDS reads use the SAME row-swizzle as A (proven conflict-free: within
// each 16-lane phase of ds_read_b128, (l4*16^l15*16) granules are distinct).
// ---------------------------------------------------------------------------
__global__ __launch_bounds__(512, 2)
void fused_kernel(const float* __restrict__ x, const float* __restrict__ y,
                  const bf16_t* __restrict__ Wc, const float* __restrict__ bc,
                  float* __restrict__ partial)
{
    __shared__ char U[LDS_BYTES];

    const int tid  = threadIdx.x;
    const int lane = tid & 63;
    const int wv   = tid >> 6;           // wave 0..7
    const int l15  = lane & 15;
    const int l4   = lane >> 4;
    const int grp  = blockIdx.x >> 1;
    const int half = blockIdx.x & 1;
    const int lc0  = wv * 32;            // local col base (within the half)
    const int gc0  = half * 256 + lc0;   // global output col base

    // --- stage Wc-half into LDS once (swizzled rows, coalesced reads)
    {
        const bf16_t* wsrc = Wc + (size_t)half * 256 * CIN;
        for (int i = tid; i < 8192; i += 512) {      // 16-B granules
            const int col = i >> 5;                  // 0..255
            const int g   = i & 31;                  // granule in row
            bf16x8 w8 = *reinterpret_cast<const bf16x8*>(wsrc + (size_t)col * CIN + g * 8);
            *reinterpret_cast<bf16x8*>(
                U + WC_LDS + (unsigned)(col * 512) +
                (((unsigned)(g * 16)) ^ ((unsigned)((col & 15) << 4)))) = w8;
        }
    }

    // staging identity: threads 0-255 stage x, 256-511 stage y; 16 thr/row
    const int sp = tid >> 8;
    const int t8 = tid & 255;
    const int sr = t8 >> 4;              // row 0..15
    const int sq = t8 & 15;              // float4 slot
    const unsigned sswz = (unsigned)((sr & 15) << 4);
    const unsigned soff = A_LDS + (unsigned)(sp * 8192 + sr * 512);
    const float* sptr = (sp ? y : x) + ((size_t)grp * (TPT * TL) + sr) * CIN;

    float4 v[4];
    auto sload = [&](const float* rowbase) {
        const float4* s4 = reinterpret_cast<const float4*>(rowbase);
#pragma unroll
        for (int c = 0; c < 4; ++c) v[c] = s4[sq + 16 * c];
    };
    auto swrite = [&]() {
        char* p = U + soff;
#pragma unroll
        for (int c = 0; c < 4; ++c) {
            const int f = sq + 16 * c;
            bf16x4 h;
            h[0] = (bf16_t)v[c].x; h[1] = (bf16_t)v[c].y;
            h[2] = (bf16_t)v[c].z; h[3] = (bf16_t)v[c].w;
            *reinterpret_cast<bf16x4*>(p + (((unsigned)(8 * f)) ^ sswz)) = h;
        }
    };

    // bias fragments, folded into acc init each tile
    f32x4 bcv[2];
#pragma unroll
    for (int cj = 0; cj < 2; ++cj) {
        float4 t4 = *reinterpret_cast<const float4*>(bc + gc0 + cj * 16 + l4 * 4);
        bcv[cj] = (f32x4){t4.x, t4.y, t4.z, t4.w};
    }

    // fragment base offsets; per-kk addr = base ^ (kk<<6) (R11-proven: the
    // kk bits are disjoint from l4*16 and XOR-associative with the swizzle)
    const unsigned fk = ((unsigned)(l4 * 16)) ^ ((unsigned)(l15 << 4));
    unsigned wbase[2];
#pragma unroll
    for (int cj = 0; cj < 2; ++cj)
        wbase[cj] = WC_LDS + (unsigned)((lc0 + cj * 16 + l15) * 512) + fk;
    const unsigned abase = A_LDS + (unsigned)(l15 * 512) + fk;

    f32x4 psum[2];
    psum[0] = (f32x4){0.f, 0.f, 0.f, 0.f};
    psum[1] = (f32x4){0.f, 0.f, 0.f, 0.f};

    // prologue: stage tile 0
    sload(sptr);
    swrite();
    __syncthreads();                     // Wc + A(tile0) ready

    for (int t = 0; t < TPT; ++t) {
        const bool pf = (t + 1 < TPT);
        if (pf) {                        // issue tile t+1 loads early (T14)
            sptr += TL * CIN;
            sload(sptr);
        }

        f32x4 accx[2], accy[2];
#pragma unroll
        for (int cj = 0; cj < 2; ++cj) { accx[cj] = bcv[cj]; accy[cj] = bcv[cj]; }

        for (int kk = 0; kk < CIN / 32; ++kk) {
            const unsigned kx = (unsigned)(kk << 6);
            bf16x8 w0 = *reinterpret_cast<const bf16x8*>(U + (wbase[0] ^ kx));
            bf16x8 w1 = *reinterpret_cast<const bf16x8*>(U + (wbase[1] ^ kx));
            bf16x8 ax = *reinterpret_cast<const bf16x8*>(U + (abase ^ kx));
            bf16x8 ay = *reinterpret_cast<const bf16x8*>(U + 8192u + (abase ^ kx));
            __builtin_amdgcn_s_setprio(1);
            accx[0] = __builtin_amdgcn_mfma_f32_16x16x32_bf16(w0, ax, accx[0], 0, 0, 0);
            accy[0] = __builtin_amdgcn_mfma_f32_16x16x32_bf16(w0, ay, accy[0], 0, 0, 0);
            accx[1] = __builtin_amdgcn_mfma_f32_16x16x32_bf16(w1, ax, accx[1], 0, 0, 0);
            accy[1] = __builtin_amdgcn_mfma_f32_16x16x32_bf16(w1, ay, accy[1], 0, 0, 0);
            __builtin_amdgcn_s_setprio(0);
        }
        __syncthreads();                 // all A(t) reads done

        if (pf) swrite();                // overwrite A with tile t+1

        // paired tanh product -> psum.
        // tanh(a)tanh(b) = (Ea-1)(Eb-1)/((Ea+1)(Eb+1)), E = e^{2v} clamped.
#pragma unroll
        for (int cj = 0; cj < 2; ++cj)
#pragma unroll
            for (int r2 = 0; r2 < 4; ++r2) {
                float a = fminf(fmaxf(accx[cj][r2], -9.0f), 9.0f);
                float c = fminf(fmaxf(accy[cj][r2], -9.0f), 9.0f);
                float Ea = exp2f(a * 2.885390081777927f);
                float Eb = exp2f(c * 2.885390081777927f);
                float num = (Ea - 1.0f) * (Eb - 1.0f);
                float den = (Ea + 1.0f) * (Eb + 1.0f);
                psum[cj][r2] += num * __builtin_amdgcn_rcpf(den);
            }

        __syncthreads();                 // A(t+1) visible before next gemm
    }

    // reduce the 16 row-lanes (l15 bits; l4 indexes the output col quad)
#pragma unroll
    for (int cj = 0; cj < 2; ++cj)
#pragma unroll
        for (int r2 = 0; r2 < 4; ++r2) {
            float s = psum[cj][r2];
            s += __shfl_xor(s, 1);
            s += __shfl_xor(s, 2);
            s += __shfl_xor(s, 4);
            s += __shfl_xor(s, 8);
            psum[cj][r2] = s;
        }
    if (l15 == 0) {
#pragma unroll
        for (int cj = 0; cj < 2; ++cj) {
            float4 o4 = make_float4(psum[cj][0], psum[cj][1], psum[cj][2], psum[cj][3]);
            *reinterpret_cast<float4*>(partial + (size_t)grp * HID + gc0 + cj * 16 + l4 * 4) = o4;
        }
    }
}

// ---------------------------------------------------------------------------
// Kernel 3: sum the 4 row-group partials per batch -> out[B][HID]
// (batch = 2048 rows = 4 groups of 512)
// ---------------------------------------------------------------------------
__global__ void reduce_kernel(const float* __restrict__ partial, float* __restrict__ out)
{
    int b = blockIdx.x;                  // 32
    int g = threadIdx.x;                 // 512
    float s = 0.f;
#pragma unroll
    for (int k = 0; k < 4; ++k)
        s += partial[((size_t)(b * 4 + k)) * HID + g];
    out[b * HID + g] = s;
}

extern "C" void kernel_launch(void* const* d_in, const int* in_sizes, int n_in,
                              void* d_out, int out_size, void* d_ws, size_t ws_size,
                              hipStream_t stream)
{
    const float* x  = (const float*)d_in[0];
    const float* y  = (const float*)d_in[1];
    const float* W1 = (const float*)d_in[2];
    const float* b1 = (const float*)d_in[3];
    const float* W2 = (const float*)d_in[4];
    const float* b2 = (const float*)d_in[5];
    float* out = (float*)d_out;

    char* ws = (char*)d_ws;
    bf16_t* Wc     = (bf16_t*)ws;                    // 256 KB
    float*  bc     = (float*)(ws + (256 << 10));     // 2 KB
    float*  partial = (float*)(ws + (264 << 10));    // 256 KB (128 grps x 512)

    hipLaunchKernelGGL(compose_kernel, dim3(HID / 8), dim3(CIN), 0, stream, W1, W2, b1, b2, Wc, bc);
    hipLaunchKernelGGL(fused_kernel, dim3(NBLK), dim3(512), 0, stream, x, y, Wc, bc, partial);
    hipLaunchKernelGGL(reduce_kernel, dim3(B_), dim3(512), 0, stream, partial, out);
}

// Round 16
// 119.169 us; speedup vs baseline: 1.5823x; 1.0376x over previous
//
#include <hip/hip_runtime.h>
#include <hip/hip_bf16.h>

#define B_   32
#define L_   2048
#define CIN  256
#define HID  512
#define TL   16
#define TPT  32                    // tiles per block = 512 rows
#define NGRP (B_ * L_ / (TL * TPT))// 128 row-groups of 512 rows
#define NBLK (NGRP * 2)            // x2 G-halves = 256 blocks = 1 per CU

// 2*log2(e): baked into Wc/bc so the gemm output feeds exp2 directly.
#define TANH_SCALE 2.885390081777927

typedef __bf16 bf16_t;
typedef __bf16 bf16x8 __attribute__((ext_vector_type(8)));
typedef __bf16 bf16x4 __attribute__((ext_vector_type(4)));
typedef float  f32x4  __attribute__((ext_vector_type(4)));

// LDS map (64 KB): A double-buffer: buf*32768 + pipe*16384 + row*512 (swz)
#define APIPE 16384u
#define ABUF  32768u

// ---------------------------------------------------------------------------
// Kernel 1: compose Wc = TANH_SCALE * (W2 @ W1) (fp32 -> bf16),
//           bc = TANH_SCALE * (W2 @ b1 + b2).
// No activation between the two 1x1 convs -> one projection, 3x fewer FLOPs.
// ---------------------------------------------------------------------------
__global__ void compose_kernel(const float* __restrict__ W1, const float* __restrict__ W2,
                               const float* __restrict__ b1, const float* __restrict__ b2,
                               bf16_t* __restrict__ Wc, float* __restrict__ bc)
{
    const int g0 = blockIdx.x * 8;       // 64 blocks
    const int c  = threadIdx.x;          // 256
    float acc[8] = {0.f, 0.f, 0.f, 0.f, 0.f, 0.f, 0.f, 0.f};
    for (int h = 0; h < HID; ++h) {
        const float w1 = W1[(size_t)h * CIN + c];   // coalesced row
#pragma unroll
        for (int k = 0; k < 8; ++k)                 // W2[g0+k][h]: uniform
            acc[k] = fmaf(W2[(size_t)(g0 + k) * HID + h], w1, acc[k]);
    }
#pragma unroll
    for (int k = 0; k < 8; ++k)
        Wc[(size_t)(g0 + k) * CIN + c] = (bf16_t)(acc[k] * (float)TANH_SCALE);
    if (c < 8) {
        const float* w2row = W2 + (size_t)(g0 + c) * HID;
        float t0 = 0.f, t1 = 0.f;
        for (int h = 0; h < HID; h += 2) {
            t0 = fmaf(w2row[h], b1[h], t0);
            t1 = fmaf(w2row[h + 1], b1[h + 1], t1);
        }
        bc[g0 + c] = (t0 + t1 + b2[g0 + c]) * (float)TANH_SCALE;
    }
}

// ---------------------------------------------------------------------------
// Kernel 2: fused GEMM + tanh-pair-product + row-reduction, weights in
// REGISTERS (the R15 diagnosis: half of the 8 MB/CU LDS traffic was each
// wave re-reading its SAME 16 weight fragments every tile; a wave's weight
// set is 32 cols x 512 B / 64 lanes = 64 VGPRs -> load once, keep forever).
// 256 blocks (1/CU) x 512 thr (8 waves). Block (grp, half): 512 rows x 256
// cols; wave w owns cols half*256 + w*32 .. +32 (cj=0,1), rows 0..15 (l15),
// both pipes. Per tile: [issue v(t+1)] gemm(REG w x LDS a) -> tanh/psum ->
// [swrite v(t+1) into idle buf] -> bar. LDS = A dbuf only (64 KB), LDS
// traffic 128 KB/tile (halved), 1 barrier/tile.
// Ledger: wreg 64 + acc 16(AGPR) + psum 8 + bcv 8 + v 16 + addr ~20 = ~135;
// launch_bounds (512,2) -> 256-reg cap -> no spill (the R2..R13 rule), 1
// block/CU. G-split x2 pairs adjacent (R15-proven: L2 absorbs the dup read).
// ---------------------------------------------------------------------------
__global__ __launch_bounds__(512, 2)
void fused_kernel(const float* __restrict__ x, const float* __restrict__ y,
                  const bf16_t* __restrict__ Wc, const float* __restrict__ bc,
                  float* __restrict__ partial)
{
    __shared__ char U[65536];            // A double-buffer

    const int tid  = threadIdx.x;
    const int lane = tid & 63;
    const int wv   = tid >> 6;           // wave 0..7
    const int l15  = lane & 15;
    const int l4   = lane >> 4;
    const int grp  = blockIdx.x >> 1;
    const int half = blockIdx.x & 1;
    const int gc0  = half * 256 + wv * 32;   // this wave's output-col base

    // --- hoist this wave's weight fragments into registers (stay resident)
    bf16x8 wreg[8][2];
#pragma unroll
    for (int kk = 0; kk < 8; ++kk)
#pragma unroll
        for (int cj = 0; cj < 2; ++cj)
            wreg[kk][cj] = *reinterpret_cast<const bf16x8*>(
                Wc + (size_t)(gc0 + cj * 16 + l15) * CIN + kk * 32 + l4 * 8);

    // bias fragments (scaled), folded into acc init each tile
    f32x4 bcv[2];
#pragma unroll
    for (int cj = 0; cj < 2; ++cj) {
        float4 t4 = *reinterpret_cast<const float4*>(bc + gc0 + cj * 16 + l4 * 4);
        bcv[cj] = (f32x4){t4.x, t4.y, t4.z, t4.w};
    }

    // staging identity: threads 0-255 stage x, 256-511 stage y; 16 thr/row
    const int sp = tid >> 8;
    const int t8 = tid & 255;
    const int sr = t8 >> 4;              // row 0..15
    const int sq = t8 & 15;              // float4 slot
    const unsigned sswz = (unsigned)((sr & 15) << 4);
    const unsigned soff = (unsigned)(sp * APIPE + sr * 512);
    const float* sptr = (sp ? y : x) + ((size_t)grp * (TPT * TL) + sr) * CIN;

    float4 v[4];
    auto sload = [&](const float* rowbase) {
        const float4* s4 = reinterpret_cast<const float4*>(rowbase);
#pragma unroll
        for (int c = 0; c < 4; ++c) v[c] = s4[sq + 16 * c];
    };
    auto swrite = [&](int buf) {
        char* p = U + (unsigned)(buf * ABUF) + soff;
#pragma unroll
        for (int c = 0; c < 4; ++c) {
            const int f = sq + 16 * c;
            bf16x4 h;
            h[0] = (bf16_t)v[c].x; h[1] = (bf16_t)v[c].y;
            h[2] = (bf16_t)v[c].z; h[3] = (bf16_t)v[c].w;
            *reinterpret_cast<bf16x4*>(p + (((unsigned)(8 * f)) ^ sswz)) = h;
        }
    };

    // A fragment base; per-kk addr = base ^ (kk<<6) (R11/R15-proven swizzle)
    const unsigned abase = (unsigned)(l15 * 512) + (((unsigned)(l4 * 16)) ^ ((unsigned)(l15 << 4)));

    f32x4 psum[2];
    psum[0] = (f32x4){0.f, 0.f, 0.f, 0.f};
    psum[1] = (f32x4){0.f, 0.f, 0.f, 0.f};

    // prologue: stage tile 0 into buf 0
    sload(sptr);
    swrite(0);
    __syncthreads();

    int cur = 0;
    for (int t = 0; t < TPT; ++t) {
        const bool pf = (t + 1 < TPT);
        if (pf) {                        // issue tile t+1 loads early (T14)
            sptr += TL * CIN;
            sload(sptr);
        }

        f32x4 accx[2], accy[2];
#pragma unroll
        for (int cj = 0; cj < 2; ++cj) { accx[cj] = bcv[cj]; accy[cj] = bcv[cj]; }

        const unsigned ab = (unsigned)(cur * ABUF);
#pragma unroll
        for (int kk = 0; kk < 8; ++kk) {
            const unsigned o = ab + (abase ^ (unsigned)(kk << 6));
            bf16x8 ax = *reinterpret_cast<const bf16x8*>(U + o);
            bf16x8 ay = *reinterpret_cast<const bf16x8*>(U + APIPE + o);
            __builtin_amdgcn_s_setprio(1);
            accx[0] = __builtin_amdgcn_mfma_f32_16x16x32_bf16(wreg[kk][0], ax, accx[0], 0, 0, 0);
            accy[0] = __builtin_amdgcn_mfma_f32_16x16x32_bf16(wreg[kk][0], ay, accy[0], 0, 0, 0);
            accx[1] = __builtin_amdgcn_mfma_f32_16x16x32_bf16(wreg[kk][1], ax, accx[1], 0, 0, 0);
            accy[1] = __builtin_amdgcn_mfma_f32_16x16x32_bf16(wreg[kk][1], ay, accy[1], 0, 0, 0);
            __builtin_amdgcn_s_setprio(0);
        }

        // paired tanh product -> psum. Scale already baked into Wc/bc:
        // acc IS the exp2 argument. tanh(a)tanh(b) = (Ea-1)(Eb-1)/((Ea+1)(Eb+1)).
#pragma unroll
        for (int cj = 0; cj < 2; ++cj)
#pragma unroll
            for (int r2 = 0; r2 < 4; ++r2) {
                float a = fminf(fmaxf(accx[cj][r2], -26.0f), 26.0f);
                float c = fminf(fmaxf(accy[cj][r2], -26.0f), 26.0f);
                float Ea = exp2f(a);
                float Eb = exp2f(c);
                float num = (Ea - 1.0f) * (Eb - 1.0f);
                float den = (Ea + 1.0f) * (Eb + 1.0f);
                psum[cj][r2] += num * __builtin_amdgcn_rcpf(den);
            }

        if (pf) swrite(cur ^ 1);         // write-late into the idle buffer
        __syncthreads();                 // publish buf[cur^1]
        cur ^= 1;
    }

    // reduce the 16 row-lanes (l15 bits; l4 indexes the output col quad)
#pragma unroll
    for (int cj = 0; cj < 2; ++cj)
#pragma unroll
        for (int r2 = 0; r2 < 4; ++r2) {
            float s = psum[cj][r2];
            s += __shfl_xor(s, 1);
            s += __shfl_xor(s, 2);
            s += __shfl_xor(s, 4);
            s += __shfl_xor(s, 8);
            psum[cj][r2] = s;
        }
    if (l15 == 0) {
#pragma unroll
        for (int cj = 0; cj < 2; ++cj) {
            float4 o4 = make_float4(psum[cj][0], psum[cj][1], psum[cj][2], psum[cj][3]);
            *reinterpret_cast<float4*>(partial + (size_t)grp * HID + gc0 + cj * 16 + l4 * 4) = o4;
        }
    }
}

// ---------------------------------------------------------------------------
// Kernel 3: sum the 4 row-group partials per batch -> out[B][HID]
// ---------------------------------------------------------------------------
__global__ void reduce_kernel(const float* __restrict__ partial, float* __restrict__ out)
{
    int b = blockIdx.x;                  // 32
    int g = threadIdx.x;                 // 512
    float s = 0.f;
#pragma unroll
    for (int k = 0; k < 4; ++k)
        s += partial[((size_t)(b * 4 + k)) * HID + g];
    out[b * HID + g] = s;
}

extern "C" void kernel_launch(void* const* d_in, const int* in_sizes, int n_in,
                              void* d_out, int out_size, void* d_ws, size_t ws_size,
                              hipStream_t stream)
{
    const float* x  = (const float*)d_in[0];
    const float* y  = (const float*)d_in[1];
    const float* W1 = (const float*)d_in[2];
    const float* b1 = (const float*)d_in[3];
    const float* W2 = (const float*)d_in[4];
    const float* b2 = (const float*)d_in[5];
    float* out = (float*)d_out;

    char* ws = (char*)d_ws;
    bf16_t* Wc     = (bf16_t*)ws;                    // 256 KB
    float*  bc     = (float*)(ws + (256 << 10));     // 2 KB
    float*  partial = (float*)(ws + (264 << 10));    // 256 KB (128 grps x 512)

    hipLaunchKernelGGL(compose_kernel, dim3(HID / 8), dim3(CIN), 0, stream, W1, W2, b1, b2, Wc, bc);
    hipLaunchKernelGGL(fused_kernel, dim3(NBLK), dim3(512), 0, stream, x, y, Wc, bc, partial);
    hipLaunchKernelGGL(reduce_kernel, dim3(B_), dim3(512), 0, stream, partial, out);
}